// Round 9
// baseline (664.851 us; speedup 1.0000x reference)
//
#include <hip/hip_runtime.h>

#define HH 64
#define VV 50257
#define BB 32
#define LL 4096

constexpr float LN_EPS_F = 1e-5f;
constexpr float DELTA_EPS_F = 1e-6f;

constexpr int CS = 64;       // chunk size (steps per chunk)
constexpr int NG = LL / CS;  // 64 chunks per batch

typedef float f32x4 __attribute__((ext_vector_type(4)));
typedef short bf16x8 __attribute__((ext_vector_type(8)));
union U16x8 { uint4 u; bf16x8 v; unsigned short s[8]; };

__device__ __forceinline__ unsigned short f2bf(float f) {
  union { float f; unsigned u; } v; v.f = f;
  unsigned r = v.u + 0x7fff + ((v.u >> 16) & 1);  // RNE
  return (unsigned short)(r >> 16);
}

// ---------------- DPP wave reduction (sum of 64 lanes -> lane 63) ----------------
template <int CTRL>
__device__ __forceinline__ float dpp_add(float x) {
  int t = __builtin_amdgcn_update_dpp(0, __float_as_int(x), CTRL, 0xF, 0xF, true);
  return x + __int_as_float(t);
}

__device__ __forceinline__ float wave_sum_lane63(float x) {
  x = dpp_add<0x111>(x);
  x = dpp_add<0x112>(x);
  x = dpp_add<0x114>(x);
  x = dpp_add<0x118>(x);
  x = dpp_add<0x142>(x);
  x = dpp_add<0x143>(x);
  return x;
}

__device__ __forceinline__ float readlane_f(float x, int lane) {
  return __int_as_float(__builtin_amdgcn_readlane(__float_as_int(x), lane));
}

// ---------------- Kernel 0: bf16 weight prep ----------------
__global__ __launch_bounds__(256) void prep_kernel(
    const float* __restrict__ w1, const float* __restrict__ w2,
    unsigned short* __restrict__ w1b, unsigned short* __restrict__ w2b) {
  int i = blockIdx.x * 256 + threadIdx.x;  // 0..16383
  if (i < 8192) {
    int jj = i >> 6, h = i & 63;
    w1b[i] = f2bf(w1[h * 128 + jj]);
  } else {
    int k = i - 8192;
    int h = k >> 7, jj = k & 127;
    w2b[k] = f2bf(w2[jj * 64 + h]);
  }
}

// ---------------- Kernel 1: encoder via bf16 MFMA — LDS overlay (28 KB) ----------
// x_l (epilogue transpose buffer) aliases e_l+act_l, which are dead after GEMM2.
__global__ __launch_bounds__(64, 1) void encoder_kernel(
    const int* __restrict__ seq, const float* __restrict__ embed,
    const unsigned short* __restrict__ w1b, const float* __restrict__ b1,
    const unsigned short* __restrict__ w2b, const float* __restrict__ b2,
    const float* __restrict__ ln_g, const float* __restrict__ ln_b,
    float* __restrict__ h_all, float* __restrict__ beta) {
  __shared__ __align__(16) char pool[26624];  // e_l(9216) + act_l(17408); x_l(16640) aliases
  unsigned short (*e_l)[72] = reinterpret_cast<unsigned short (*)[72]>(pool);
  unsigned short (*act_l)[136] = reinterpret_cast<unsigned short (*)[136]>(pool + 9216);
  float (*x_l)[65] = reinterpret_cast<float (*)[65]>(pool);
  __shared__ float2 gb_l[64];
  __shared__ float b1_l[128], b2_l[64];

  int lane = threadIdx.x;
  int q = lane >> 4, l = lane & 15;
  int base = blockIdx.x * 64;
  int s = seq[base + lane];

  {
    const float4* ep = reinterpret_cast<const float4*>(embed + (size_t)s * HH);
#pragma unroll
    for (int i = 0; i < 8; ++i) {
      float4 va = ep[2 * i], vb = ep[2 * i + 1];
      uint4 u;
      u.x = (unsigned)f2bf(va.x) | ((unsigned)f2bf(va.y) << 16);
      u.y = (unsigned)f2bf(va.z) | ((unsigned)f2bf(va.w) << 16);
      u.z = (unsigned)f2bf(vb.x) | ((unsigned)f2bf(vb.y) << 16);
      u.w = (unsigned)f2bf(vb.z) | ((unsigned)f2bf(vb.w) << 16);
      *(uint4*)&e_l[lane][8 * i] = u;
    }
  }
  gb_l[lane] = make_float2(ln_g[lane], ln_b[lane]);
  b1_l[lane] = b1[lane];
  b1_l[64 + lane] = b1[64 + lane];
  b2_l[lane] = b2[lane];

  bf16x8 af1[8][2];
#pragma unroll
  for (int mi = 0; mi < 8; ++mi)
#pragma unroll
    for (int ks = 0; ks < 2; ++ks) {
      U16x8 t;
      t.u = *(const uint4*)(w1b + (mi * 16 + l) * 64 + ks * 32 + q * 8);
      af1[mi][ks] = t.v;
    }

  __syncthreads();

  f32x4 acc1[8][4];
#pragma unroll
  for (int mi = 0; mi < 8; ++mi)
#pragma unroll
    for (int nt = 0; nt < 4; ++nt) acc1[mi][nt] = (f32x4){0.f, 0.f, 0.f, 0.f};

#pragma unroll
  for (int ks = 0; ks < 2; ++ks) {
    bf16x8 bfr[4];
#pragma unroll
    for (int nt = 0; nt < 4; ++nt) {
      U16x8 t;
      t.u = *(const uint4*)&e_l[nt * 16 + l][ks * 32 + q * 8];
      bfr[nt] = t.v;
    }
#pragma unroll
    for (int mi = 0; mi < 8; ++mi)
#pragma unroll
      for (int nt = 0; nt < 4; ++nt)
        acc1[mi][nt] = __builtin_amdgcn_mfma_f32_16x16x32_bf16(
            af1[mi][ks], bfr[nt], acc1[mi][nt], 0, 0, 0);
  }

#pragma unroll
  for (int mi = 0; mi < 8; ++mi)
#pragma unroll
    for (int nt = 0; nt < 4; ++nt) {
      int tok = nt * 16 + l;
      int jj0 = mi * 16 + q * 4;
      float v0 = fmaxf(acc1[mi][nt][0] + b1_l[jj0 + 0], 0.f);
      float v1 = fmaxf(acc1[mi][nt][1] + b1_l[jj0 + 1], 0.f);
      float v2 = fmaxf(acc1[mi][nt][2] + b1_l[jj0 + 2], 0.f);
      float v3 = fmaxf(acc1[mi][nt][3] + b1_l[jj0 + 3], 0.f);
      uint2 u;
      u.x = (unsigned)f2bf(v0) | ((unsigned)f2bf(v1) << 16);
      u.y = (unsigned)f2bf(v2) | ((unsigned)f2bf(v3) << 16);
      *(uint2*)&act_l[tok][jj0] = u;
    }

  bf16x8 bf2[4][4];
#pragma unroll
  for (int nt = 0; nt < 4; ++nt)
#pragma unroll
    for (int ks = 0; ks < 4; ++ks) {
      U16x8 t;
      t.u = *(const uint4*)(w2b + (nt * 16 + l) * 128 + ks * 32 + q * 8);
      bf2[nt][ks] = t.v;
    }

  __syncthreads();

  f32x4 acc2[4][4];
#pragma unroll
  for (int mt = 0; mt < 4; ++mt)
#pragma unroll
    for (int nt = 0; nt < 4; ++nt) acc2[mt][nt] = (f32x4){0.f, 0.f, 0.f, 0.f};

#pragma unroll
  for (int ks = 0; ks < 4; ++ks) {
    bf16x8 afr[4];
#pragma unroll
    for (int mt = 0; mt < 4; ++mt) {
      U16x8 t;
      t.u = *(const uint4*)&act_l[mt * 16 + l][ks * 32 + q * 8];
      afr[mt] = t.v;
    }
#pragma unroll
    for (int mt = 0; mt < 4; ++mt)
#pragma unroll
      for (int nt = 0; nt < 4; ++nt)
        acc2[mt][nt] = __builtin_amdgcn_mfma_f32_16x16x32_bf16(
            afr[mt], bf2[nt][ks], acc2[mt][nt], 0, 0, 0);
  }

  __syncthreads();  // act_l/e_l reads complete before x_l (alias) writes

#pragma unroll
  for (int mt = 0; mt < 4; ++mt)
#pragma unroll
    for (int nt = 0; nt < 4; ++nt) {
      int h = nt * 16 + l;
#pragma unroll
      for (int r = 0; r < 4; ++r) {
        int tok = mt * 16 + q * 4 + r;
        x_l[tok][h] = acc2[mt][nt][r] + b2_l[h];
      }
    }

  __syncthreads();

  float x[HH];
#pragma unroll
  for (int h = 0; h < HH; ++h) x[h] = x_l[lane][h];
  {
    const float4* ep = reinterpret_cast<const float4*>(embed + (size_t)s * HH);
#pragma unroll
    for (int i = 0; i < 16; ++i) {
      float4 v = ep[i];
      x[4 * i + 0] += v.x; x[4 * i + 1] += v.y;
      x[4 * i + 2] += v.z; x[4 * i + 3] += v.w;
    }
  }
  float sum = 0.f;
#pragma unroll
  for (int h = 0; h < HH; ++h) sum += x[h];
  float mu = sum * (1.f / HH);
  float vs = 0.f;
#pragma unroll
  for (int h = 0; h < HH; ++h) { float dx = x[h] - mu; vs = fmaf(dx, dx, vs); }
  float rstd = rsqrtf(vs * (1.f / HH) + LN_EPS_F);

  float ss = 0.f;
#pragma unroll
  for (int h = 0; h < HH; ++h) {
    float2 gb = gb_l[h];
    float o = fmaf((x[h] - mu) * rstd, gb.x, gb.y);
    ss = fmaf(o, o, ss);
    x[h] = o;
  }
  float4* hp = reinterpret_cast<float4*>(h_all + (size_t)(base + lane) * HH);
#pragma unroll
  for (int i = 0; i < 16; ++i)
    hp[i] = make_float4(x[4 * i + 0], x[4 * i + 1], x[4 * i + 2], x[4 * i + 3]);
  beta[base + lane] = 1.f / (ss + DELTA_EPS_F);
}

// ---------------- Kernel 2: Gram + m-recurrence + materialized N^T ----------------
// LDS overlay (37.1 KB): poolA = K staging -> (beta M)^T; poolB = Gl -> colS (K^T).
__global__ __launch_bounds__(64, 1) void gram_n_kernel(
    const float* __restrict__ h_all, const float* __restrict__ beta,
    float* __restrict__ Ng) {
  __shared__ __align__(16) char smem[37120];
  unsigned short (*pA)[64][72] = reinterpret_cast<unsigned short (*)[64][72]>(smem);           // 18432 B
  float (*Gl)[68] = reinterpret_cast<float (*)[68]>(smem + 18432);                             // 17408 B
  unsigned short (*pC)[64][72] = reinterpret_cast<unsigned short (*)[64][72]>(smem + 18432);   // 18432 B (aliases Gl)
  float* bl = reinterpret_cast<float*>(smem + 36864);                                          // 256 B

  int c = blockIdx.x, b = blockIdx.y, lane = threadIdx.x;
  int q = lane >> 4, l = lane & 15;
  const float* src = h_all + ((size_t)b * LL + c * CS) * HH;

  // ---- stage K rows (bf16 hi/lo) for the Gram MFMA
#pragma unroll
  for (int i = 0; i < 16; ++i) {
    int row = i * 4 + q;
    float4 v = *(const float4*)&src[row * 64 + l * 4];
    float f[4] = {v.x, v.y, v.z, v.w};
    unsigned hs[4], ls[4];
#pragma unroll
    for (int r = 0; r < 4; ++r) {
      unsigned short hb = f2bf(f[r]);
      float hf = __uint_as_float(((unsigned)hb) << 16);
      hs[r] = hb; ls[r] = f2bf(f[r] - hf);
    }
    *(uint2*)&pA[0][row][l * 4] = make_uint2(hs[0] | (hs[1] << 16), hs[2] | (hs[3] << 16));
    *(uint2*)&pA[1][row][l * 4] = make_uint2(ls[0] | (ls[1] << 16), ls[2] | (ls[3] << 16));
  }
  bl[lane] = beta[(size_t)b * LL + c * CS + lane];
  if (c == NG - 1) { pA[0][63][lane] = 0; pA[1][63][lane] = 0; }  // t=L-1 not a key
  __syncthreads();

  // ---- Gram via split-bf16 MFMA: D[s][t] = sum_h K[s][h] K[t][h]
  f32x4 acc[4][4];
#pragma unroll
  for (int mi = 0; mi < 4; ++mi)
#pragma unroll
    for (int nt = 0; nt < 4; ++nt) acc[mi][nt] = (f32x4){0.f, 0.f, 0.f, 0.f};

#pragma unroll
  for (int ks = 0; ks < 2; ++ks) {
    bf16x8 ah[4], al_[4];
#pragma unroll
    for (int i = 0; i < 4; ++i) {
      U16x8 t;
      t.u = *(const uint4*)&pA[0][i * 16 + l][ks * 32 + q * 8]; ah[i] = t.v;
      t.u = *(const uint4*)&pA[1][i * 16 + l][ks * 32 + q * 8]; al_[i] = t.v;
    }
#pragma unroll
    for (int mi = 0; mi < 4; ++mi)
#pragma unroll
      for (int nt = 0; nt < 4; ++nt) {
        acc[mi][nt] = __builtin_amdgcn_mfma_f32_16x16x32_bf16(ah[mi], ah[nt], acc[mi][nt], 0, 0, 0);
        acc[mi][nt] = __builtin_amdgcn_mfma_f32_16x16x32_bf16(ah[mi], al_[nt], acc[mi][nt], 0, 0, 0);
        acc[mi][nt] = __builtin_amdgcn_mfma_f32_16x16x32_bf16(al_[mi], ah[nt], acc[mi][nt], 0, 0, 0);
      }
  }

  // ---- write Gl[s][t] = beta_s * G  (poolB)
#pragma unroll
  for (int mi = 0; mi < 4; ++mi) {
    int s0 = mi * 16 + q * 4;
    float4 b4 = *(const float4*)&bl[s0];
#pragma unroll
    for (int nt = 0; nt < 4; ++nt) {
      int t = nt * 16 + l;
      Gl[s0 + 0][t] = acc[mi][nt][0] * b4.x;
      Gl[s0 + 1][t] = acc[mi][nt][1] * b4.y;
      Gl[s0 + 2][t] = acc[mi][nt][2] * b4.z;
      Gl[s0 + 3][t] = acc[mi][nt][3] * b4.w;
    }
  }
  __syncthreads();

  // ---- K column into regs (lane = h)
  float m[64];
#pragma unroll
  for (int t = 0; t < 64; ++t) m[t] = src[t * 64 + lane];
  if (c == NG - 1) m[63] = 0.f;

  // ---- m-recurrence (exact f32; uniform float4 LDS reads of Gl rows)
#pragma unroll
  for (int s = 63; s >= 1; --s) {
    float ms = m[s];
    const float* g = &Gl[s][0];
#pragma unroll
    for (int i = 0; i + 3 < s; i += 4) {
      float4 g4 = *(const float4*)(g + i);
      m[i + 0] = fmaf(-g4.x, ms, m[i + 0]);
      m[i + 1] = fmaf(-g4.y, ms, m[i + 1]);
      m[i + 2] = fmaf(-g4.z, ms, m[i + 2]);
      m[i + 3] = fmaf(-g4.w, ms, m[i + 3]);
    }
    for (int t = s & ~3; t < s; ++t) m[t] = fmaf(-g[t], ms, m[t]);
  }

  __syncthreads();  // all Gl reads done before colS overwrites poolB

  // ---- rebuild K^T (bf16 hi/lo) into poolB from global (L2-hot), zero t=L-1
#pragma unroll
  for (int i = 0; i < 32; ++i) {
    float v0 = src[(2 * i) * 64 + lane];
    float v1 = src[(2 * i + 1) * 64 + lane];
    if (c == NG - 1 && i == 31) v1 = 0.f;
    unsigned short h0 = f2bf(v0), h1 = f2bf(v1);
    float r0 = v0 - __uint_as_float(((unsigned)h0) << 16);
    float r1 = v1 - __uint_as_float(((unsigned)h1) << 16);
    *(unsigned*)&pC[0][lane][2 * i] = (unsigned)h0 | (((unsigned)h1) << 16);
    *(unsigned*)&pC[1][lane][2 * i] = (unsigned)f2bf(r0) | (((unsigned)f2bf(r1)) << 16);
  }

  // ---- write (beta M)^T rows into poolA (K staging dead)
#pragma unroll
  for (int i = 0; i < 32; ++i) {
    float v0 = bl[2 * i] * m[2 * i];
    float v1 = bl[2 * i + 1] * m[2 * i + 1];
    unsigned short h0 = f2bf(v0), h1 = f2bf(v1);
    float r0 = v0 - __uint_as_float(((unsigned)h0) << 16);
    float r1 = v1 - __uint_as_float(((unsigned)h1) << 16);
    *(unsigned*)&pA[0][lane][2 * i] = (unsigned)h0 | (((unsigned)h1) << 16);
    *(unsigned*)&pA[1][lane][2 * i] = (unsigned)f2bf(r0) | (((unsigned)f2bf(r1)) << 16);
  }
  __syncthreads();

  // ---- N MFMA: D2[h][h'] = sum_t KT[h][t] * (beta_t m_t[h']);  N = I - D2
  f32x4 acc2[4][4];
#pragma unroll
  for (int mi = 0; mi < 4; ++mi)
#pragma unroll
    for (int nt = 0; nt < 4; ++nt) acc2[mi][nt] = (f32x4){0.f, 0.f, 0.f, 0.f};

#pragma unroll
  for (int ks = 0; ks < 2; ++ks) {
    bf16x8 ah[4], al_[4], bh[4], blo[4];
#pragma unroll
    for (int i = 0; i < 4; ++i) {
      U16x8 t;
      t.u = *(const uint4*)&pC[0][i * 16 + l][ks * 32 + q * 8]; ah[i] = t.v;
      t.u = *(const uint4*)&pC[1][i * 16 + l][ks * 32 + q * 8]; al_[i] = t.v;
      t.u = *(const uint4*)&pA[0][i * 16 + l][ks * 32 + q * 8]; bh[i] = t.v;
      t.u = *(const uint4*)&pA[1][i * 16 + l][ks * 32 + q * 8]; blo[i] = t.v;
    }
#pragma unroll
    for (int mi = 0; mi < 4; ++mi)
#pragma unroll
      for (int nt = 0; nt < 4; ++nt) {
        acc2[mi][nt] = __builtin_amdgcn_mfma_f32_16x16x32_bf16(ah[mi], bh[nt], acc2[mi][nt], 0, 0, 0);
        acc2[mi][nt] = __builtin_amdgcn_mfma_f32_16x16x32_bf16(ah[mi], blo[nt], acc2[mi][nt], 0, 0, 0);
        acc2[mi][nt] = __builtin_amdgcn_mfma_f32_16x16x32_bf16(al_[mi], bh[nt], acc2[mi][nt], 0, 0, 0);
      }
  }

  // store TRANSPOSED: Ng[j*64 + h] = N[h][j]  (float4 over h)
  float* np = Ng + (((size_t)b * NG + c) << 12);
#pragma unroll
  for (int mi = 0; mi < 4; ++mi)
#pragma unroll
    for (int nt = 0; nt < 4; ++nt) {
      int h0 = mi * 16 + q * 4, hp = nt * 16 + l;
      float4 v;
      v.x = ((h0 + 0 == hp) ? 1.f : 0.f) - acc2[mi][nt][0];
      v.y = ((h0 + 1 == hp) ? 1.f : 0.f) - acc2[mi][nt][1];
      v.z = ((h0 + 2 == hp) ? 1.f : 0.f) - acc2[mi][nt][2];
      v.w = ((h0 + 3 == hp) ? 1.f : 0.f) - acc2[mi][nt][3];
      *(float4*)&np[hp * 64 + h0] = v;
    }
}

// ---------------- Kernel 3: boundary — LDS double-buffered matvec (unchanged) -----
__global__ __launch_bounds__(64, 1) void boundary_kernel(
    const float* __restrict__ h_all, const float* __restrict__ Ng,
    const int* __restrict__ read_pos_p, float* __restrict__ Qg) {
  __shared__ __align__(16) float nt0[64 * 64];
  __shared__ __align__(16) float nt1[64 * 64];
  __shared__ __align__(16) float ql[64];

  int b = blockIdx.x, lane = threadIdx.x;
  int rpv = read_pos_p[0];
  int pos = rpv < 0 ? rpv + LL : rpv;
  float Q = h_all[((size_t)b * LL + pos) * HH + lane];

  const float* Nb = Ng + ((size_t)b * NG << 12);

  auto load_chunk = [&](float* buf, int c) {
    const float* g = Nb + ((size_t)c << 12);
#pragma unroll
    for (int i = 0; i < 16; ++i)
      __builtin_amdgcn_global_load_lds(
          (const __attribute__((address_space(1))) unsigned*)(g + i * 256 + lane * 4),
          (__attribute__((address_space(3))) unsigned*)(buf + i * 256), 16, 0, 0);
  };

  auto step = [&](const float* buf, int c, bool last) {
    if (last) __builtin_amdgcn_s_waitcnt(0x0F70);  // vmcnt(0)
    else      __builtin_amdgcn_s_waitcnt(0x4F70);  // vmcnt(16)
    Qg[((size_t)b * NG + c) * HH + lane] = Q;
    ql[lane] = Q;
    float a0 = 0.f, a1 = 0.f, a2 = 0.f, a3 = 0.f;
#pragma unroll
    for (int j = 0; j < 64; j += 4) {
      float4 q4 = *(const float4*)&ql[j];  // uniform LDS broadcast
      a0 = fmaf(buf[(j + 0) * 64 + lane], q4.x, a0);
      a1 = fmaf(buf[(j + 1) * 64 + lane], q4.y, a1);
      a2 = fmaf(buf[(j + 2) * 64 + lane], q4.z, a2);
      a3 = fmaf(buf[(j + 3) * 64 + lane], q4.w, a3);
    }
    Q = (a0 + a1) + (a2 + a3);
  };

  load_chunk(nt1, NG - 1);
  load_chunk(nt0, NG - 2);

#pragma unroll 1
  for (int c = NG - 1; c >= 1; c -= 2) {
    step(nt1, c, false);
    __builtin_amdgcn_s_waitcnt(0xC07F);  // lgkmcnt(0)
    if (c >= 3) load_chunk(nt1, c - 2);
    step(nt0, c - 1, c == 1);
    __builtin_amdgcn_s_waitcnt(0xC07F);
    if (c >= 3) load_chunk(nt0, c - 3);
  }
}

// ---------------- Kernel 4 (phase 3): parallel within-chunk r accumulation -------
__global__ __launch_bounds__(64, 1) void chunk_scan_kernel(
    const float* __restrict__ h_all, const float* __restrict__ beta,
    const float* __restrict__ Qg, float* __restrict__ rc) {
  int c = blockIdx.x, b = blockIdx.y, j = threadIdx.x;
  const float* hb = h_all + (size_t)b * LL * HH;
  const float* betab = beta + (size_t)b * LL;

  float P = Qg[((size_t)b * NG + c) * HH + j];
  float r = 0.f;

  float kk[CS];
#pragma unroll
  for (int i = 0; i < CS; ++i) kk[i] = hb[((size_t)(c * CS + i)) * HH + j];
  float bv = betab[c * CS + j];

  bool last = (c == NG - 1);
#pragma unroll
  for (int i = CS - 1; i >= 0; --i) {
    float k = kk[i];
    float bt = readlane_f(bv, i);
    float m = k * P;
    float s = wave_sum_lane63(m);
    float d = readlane_f(s, 63);
    if (i == CS - 1 && last) d = 0.f;
    r = fmaf(d, k, r);
    P = fmaf(-(bt * d), k, P);
  }
  rc[((size_t)b * NG + c) * HH + j] = r;
}

// ---------------- Kernel 5: combine r over chunks, y = r @ rp_w + rp_b ----------
__global__ __launch_bounds__(64, 1) void combine_kernel(
    const float* __restrict__ rc, const float* __restrict__ rp_w,
    const float* __restrict__ rp_b, float* __restrict__ yv) {
  int b = blockIdx.x, j = threadIdx.x;
  float r = 0.f;
#pragma unroll 8
  for (int cc = 0; cc < NG; ++cc) r += rc[((size_t)b * NG + cc) * HH + j];
  __shared__ float rs[HH];
  rs[j] = r;
  __syncthreads();
  float yj = rp_b[j];
#pragma unroll
  for (int h = 0; h < HH; ++h) yj = fmaf(rs[h], rp_w[h * HH + j], yj);
  yv[b * HH + j] = yj;
}

// ---------------- Kernel 6: output GEMM ----------------
__global__ __launch_bounds__(256, 2) void out_kernel(
    const float* __restrict__ yv, const float* __restrict__ out_w,
    const float* __restrict__ out_b, float* __restrict__ out) {
  __shared__ float ys[BB * HH];
  for (int i = threadIdx.x; i < BB * HH; i += 256) ys[i] = yv[i];
  __syncthreads();

  int v = blockIdx.x * 256 + threadIdx.x;
  if (v >= VV) return;

  float acc[BB];
  float ob = out_b[v];
#pragma unroll
  for (int b = 0; b < BB; ++b) acc[b] = ob;

  for (int h = 0; h < HH; ++h) {
    float w = out_w[(size_t)h * VV + v];
#pragma unroll
    for (int b = 0; b < BB; ++b) acc[b] = fmaf(ys[b * HH + h], w, acc[b]);
  }
#pragma unroll
  for (int b = 0; b < BB; ++b) out[(size_t)b * VV + v] = acc[b];
}

// ---------------- launch ----------------
extern "C" void kernel_launch(void* const* d_in, const int* in_sizes, int n_in,
                              void* d_out, int out_size, void* d_ws, size_t ws_size,
                              hipStream_t stream) {
  (void)in_sizes; (void)n_in; (void)out_size; (void)ws_size;
  const int*   seq   = (const int*)d_in[0];
  const int*   rp    = (const int*)d_in[1];
  const float* embed = (const float*)d_in[2];
  const float* w1    = (const float*)d_in[3];
  const float* b1    = (const float*)d_in[4];
  const float* w2    = (const float*)d_in[5];
  const float* b2    = (const float*)d_in[6];
  const float* ln_g  = (const float*)d_in[7];
  const float* ln_b  = (const float*)d_in[8];
  const float* rp_w  = (const float*)d_in[9];
  const float* rp_b  = (const float*)d_in[10];
  const float* out_w = (const float*)d_in[11];
  const float* out_b = (const float*)d_in[12];
  float* out = (float*)d_out;

  // workspace layout (~68.6 MB)
  float* h_all = (float*)d_ws;                               // B*L*H
  float* beta  = h_all + (size_t)BB * LL * HH;               // B*L
  float* Ng    = beta + (size_t)BB * LL;                     // B*NG*H*H (32 MB, N^T)
  float* Qg    = Ng + (size_t)BB * NG * HH * HH;             // B*NG*H
  float* rcv   = Qg + (size_t)BB * NG * HH;                  // B*NG*H
  float* yv    = rcv + (size_t)BB * NG * HH;                 // B*H
  unsigned short* w1b = (unsigned short*)(yv + (size_t)BB * HH);  // 128*64 bf16
  unsigned short* w2b = w1b + 8192;                               // 64*128 bf16

  prep_kernel<<<64, 256, 0, stream>>>(w1, w2, w1b, w2b);
  encoder_kernel<<<BB * LL / 64, 64, 0, stream>>>(seq, embed, w1b, b1, w2b, b2,
                                                  ln_g, ln_b, h_all, beta);
  gram_n_kernel<<<dim3(NG, BB), 64, 0, stream>>>(h_all, beta, Ng);
  boundary_kernel<<<BB, 64, 0, stream>>>(h_all, Ng, rp, Qg);
  chunk_scan_kernel<<<dim3(NG, BB), 64, 0, stream>>>(h_all, beta, Qg, rcv);
  combine_kernel<<<BB, 64, 0, stream>>>(rcv, rp_w, rp_b, yv);
  out_kernel<<<(VV + 255) / 256, 256, 0, stream>>>(yv, out_w, out_b, out);
}

// Round 10
// 229.744 us; speedup vs baseline: 2.8939x; 2.8939x over previous
//
#include <hip/hip_runtime.h>

#define HH 64
#define VV 50257
#define BB 32
#define LL 4096

constexpr float LN_EPS_F = 1e-5f;
constexpr float DELTA_EPS_F = 1e-6f;

constexpr int CS = 64;       // chunk size (steps per chunk)
constexpr int NG = LL / CS;  // 64 chunks per batch

typedef float f32x4 __attribute__((ext_vector_type(4)));
typedef short bf16x8 __attribute__((ext_vector_type(8)));
union U16x8 { uint4 u; bf16x8 v; unsigned short s[8]; };

__device__ __forceinline__ unsigned short f2bf(float f) {
  union { float f; unsigned u; } v; v.f = f;
  unsigned r = v.u + 0x7fff + ((v.u >> 16) & 1);  // RNE
  return (unsigned short)(r >> 16);
}

// ---------------- DPP wave reduction (sum of 64 lanes -> lane 63) ----------------
template <int CTRL>
__device__ __forceinline__ float dpp_add(float x) {
  int t = __builtin_amdgcn_update_dpp(0, __float_as_int(x), CTRL, 0xF, 0xF, true);
  return x + __int_as_float(t);
}

__device__ __forceinline__ float wave_sum_lane63(float x) {
  x = dpp_add<0x111>(x);
  x = dpp_add<0x112>(x);
  x = dpp_add<0x114>(x);
  x = dpp_add<0x118>(x);
  x = dpp_add<0x142>(x);
  x = dpp_add<0x143>(x);
  return x;
}

__device__ __forceinline__ float readlane_f(float x, int lane) {
  return __int_as_float(__builtin_amdgcn_readlane(__float_as_int(x), lane));
}

// ---------------- Kernel 0: bf16 weight prep ----------------
__global__ __launch_bounds__(256) void prep_kernel(
    const float* __restrict__ w1, const float* __restrict__ w2,
    unsigned short* __restrict__ w1b, unsigned short* __restrict__ w2b) {
  int i = blockIdx.x * 256 + threadIdx.x;  // 0..16383
  if (i < 8192) {
    int jj = i >> 6, h = i & 63;
    w1b[i] = f2bf(w1[h * 128 + jj]);
  } else {
    int k = i - 8192;
    int h = k >> 7, jj = k & 127;
    w2b[k] = f2bf(w2[jj * 64 + h]);
  }
}

// ---------------- Kernel 1: encoder via bf16 MFMA — LDS overlay (28 KB) ----------
__global__ __launch_bounds__(64, 1) void encoder_kernel(
    const int* __restrict__ seq, const float* __restrict__ embed,
    const unsigned short* __restrict__ w1b, const float* __restrict__ b1,
    const unsigned short* __restrict__ w2b, const float* __restrict__ b2,
    const float* __restrict__ ln_g, const float* __restrict__ ln_b,
    float* __restrict__ h_all, float* __restrict__ beta) {
  __shared__ __align__(16) char pool[26624];  // e_l(9216) + act_l(17408); x_l(16640) aliases
  unsigned short (*e_l)[72] = reinterpret_cast<unsigned short (*)[72]>(pool);
  unsigned short (*act_l)[136] = reinterpret_cast<unsigned short (*)[136]>(pool + 9216);
  float (*x_l)[65] = reinterpret_cast<float (*)[65]>(pool);
  __shared__ float2 gb_l[64];
  __shared__ float b1_l[128], b2_l[64];

  int lane = threadIdx.x;
  int q = lane >> 4, l = lane & 15;
  int base = blockIdx.x * 64;
  int s = seq[base + lane];

  {
    const float4* ep = reinterpret_cast<const float4*>(embed + (size_t)s * HH);
#pragma unroll
    for (int i = 0; i < 8; ++i) {
      float4 va = ep[2 * i], vb = ep[2 * i + 1];
      uint4 u;
      u.x = (unsigned)f2bf(va.x) | ((unsigned)f2bf(va.y) << 16);
      u.y = (unsigned)f2bf(va.z) | ((unsigned)f2bf(va.w) << 16);
      u.z = (unsigned)f2bf(vb.x) | ((unsigned)f2bf(vb.y) << 16);
      u.w = (unsigned)f2bf(vb.z) | ((unsigned)f2bf(vb.w) << 16);
      *(uint4*)&e_l[lane][8 * i] = u;
    }
  }
  gb_l[lane] = make_float2(ln_g[lane], ln_b[lane]);
  b1_l[lane] = b1[lane];
  b1_l[64 + lane] = b1[64 + lane];
  b2_l[lane] = b2[lane];

  bf16x8 af1[8][2];
#pragma unroll
  for (int mi = 0; mi < 8; ++mi)
#pragma unroll
    for (int ks = 0; ks < 2; ++ks) {
      U16x8 t;
      t.u = *(const uint4*)(w1b + (mi * 16 + l) * 64 + ks * 32 + q * 8);
      af1[mi][ks] = t.v;
    }

  __syncthreads();

  f32x4 acc1[8][4];
#pragma unroll
  for (int mi = 0; mi < 8; ++mi)
#pragma unroll
    for (int nt = 0; nt < 4; ++nt) acc1[mi][nt] = (f32x4){0.f, 0.f, 0.f, 0.f};

#pragma unroll
  for (int ks = 0; ks < 2; ++ks) {
    bf16x8 bfr[4];
#pragma unroll
    for (int nt = 0; nt < 4; ++nt) {
      U16x8 t;
      t.u = *(const uint4*)&e_l[nt * 16 + l][ks * 32 + q * 8];
      bfr[nt] = t.v;
    }
#pragma unroll
    for (int mi = 0; mi < 8; ++mi)
#pragma unroll
      for (int nt = 0; nt < 4; ++nt)
        acc1[mi][nt] = __builtin_amdgcn_mfma_f32_16x16x32_bf16(
            af1[mi][ks], bfr[nt], acc1[mi][nt], 0, 0, 0);
  }

#pragma unroll
  for (int mi = 0; mi < 8; ++mi)
#pragma unroll
    for (int nt = 0; nt < 4; ++nt) {
      int tok = nt * 16 + l;
      int jj0 = mi * 16 + q * 4;
      float v0 = fmaxf(acc1[mi][nt][0] + b1_l[jj0 + 0], 0.f);
      float v1 = fmaxf(acc1[mi][nt][1] + b1_l[jj0 + 1], 0.f);
      float v2 = fmaxf(acc1[mi][nt][2] + b1_l[jj0 + 2], 0.f);
      float v3 = fmaxf(acc1[mi][nt][3] + b1_l[jj0 + 3], 0.f);
      uint2 u;
      u.x = (unsigned)f2bf(v0) | ((unsigned)f2bf(v1) << 16);
      u.y = (unsigned)f2bf(v2) | ((unsigned)f2bf(v3) << 16);
      *(uint2*)&act_l[tok][jj0] = u;
    }

  bf16x8 bf2[4][4];
#pragma unroll
  for (int nt = 0; nt < 4; ++nt)
#pragma unroll
    for (int ks = 0; ks < 4; ++ks) {
      U16x8 t;
      t.u = *(const uint4*)(w2b + (nt * 16 + l) * 128 + ks * 32 + q * 8);
      bf2[nt][ks] = t.v;
    }

  __syncthreads();

  f32x4 acc2[4][4];
#pragma unroll
  for (int mt = 0; mt < 4; ++mt)
#pragma unroll
    for (int nt = 0; nt < 4; ++nt) acc2[mt][nt] = (f32x4){0.f, 0.f, 0.f, 0.f};

#pragma unroll
  for (int ks = 0; ks < 4; ++ks) {
    bf16x8 afr[4];
#pragma unroll
    for (int mt = 0; mt < 4; ++mt) {
      U16x8 t;
      t.u = *(const uint4*)&act_l[mt * 16 + l][ks * 32 + q * 8];
      afr[mt] = t.v;
    }
#pragma unroll
    for (int mt = 0; mt < 4; ++mt)
#pragma unroll
      for (int nt = 0; nt < 4; ++nt)
        acc2[mt][nt] = __builtin_amdgcn_mfma_f32_16x16x32_bf16(
            afr[mt], bf2[nt][ks], acc2[mt][nt], 0, 0, 0);
  }

  __syncthreads();  // act_l/e_l reads complete before x_l (alias) writes

#pragma unroll
  for (int mt = 0; mt < 4; ++mt)
#pragma unroll
    for (int nt = 0; nt < 4; ++nt) {
      int h = nt * 16 + l;
#pragma unroll
      for (int r = 0; r < 4; ++r) {
        int tok = mt * 16 + q * 4 + r;
        x_l[tok][h] = acc2[mt][nt][r] + b2_l[h];
      }
    }

  __syncthreads();

  float x[HH];
#pragma unroll
  for (int h = 0; h < HH; ++h) x[h] = x_l[lane][h];
  {
    const float4* ep = reinterpret_cast<const float4*>(embed + (size_t)s * HH);
#pragma unroll
    for (int i = 0; i < 16; ++i) {
      float4 v = ep[i];
      x[4 * i + 0] += v.x; x[4 * i + 1] += v.y;
      x[4 * i + 2] += v.z; x[4 * i + 3] += v.w;
    }
  }
  float sum = 0.f;
#pragma unroll
  for (int h = 0; h < HH; ++h) sum += x[h];
  float mu = sum * (1.f / HH);
  float vs = 0.f;
#pragma unroll
  for (int h = 0; h < HH; ++h) { float dx = x[h] - mu; vs = fmaf(dx, dx, vs); }
  float rstd = rsqrtf(vs * (1.f / HH) + LN_EPS_F);

  float ss = 0.f;
#pragma unroll
  for (int h = 0; h < HH; ++h) {
    float2 gb = gb_l[h];
    float o = fmaf((x[h] - mu) * rstd, gb.x, gb.y);
    ss = fmaf(o, o, ss);
    x[h] = o;
  }
  float4* hp = reinterpret_cast<float4*>(h_all + (size_t)(base + lane) * HH);
#pragma unroll
  for (int i = 0; i < 16; ++i)
    hp[i] = make_float4(x[4 * i + 0], x[4 * i + 1], x[4 * i + 2], x[4 * i + 3]);
  beta[base + lane] = 1.f / (ss + DELTA_EPS_F);
}

// ---------------- Kernel 2: Gram + m-recurrence + materialized N^T ----------------
// 37.1 KB overlay with r8's SAFE dataflow order:
//   poolA: K-row staging (Gram) -> colS = K^T (built from m INITIAL, pre-recurrence)
//   poolB: Gl (recurrence coeffs) -> (beta M)^T (post-recurrence; Gl dead)
// No global re-reads, no extended live ranges -> no spill (r9 lesson).
__global__ __launch_bounds__(64, 1) void gram_n_kernel(
    const float* __restrict__ h_all, const float* __restrict__ beta,
    float* __restrict__ Ng) {
  __shared__ __align__(16) char smem[37120];
  unsigned short (*pA)[64][72] = reinterpret_cast<unsigned short (*)[64][72]>(smem);          // 18432 B
  unsigned short (*pB)[64][72] = reinterpret_cast<unsigned short (*)[64][72]>(smem + 18432);  // 18432 B
  float (*Gl)[68] = reinterpret_cast<float (*)[68]>(smem + 18432);                            // 17408 B (in pB)
  float* bl = reinterpret_cast<float*>(smem + 36864);                                         // 256 B

  int c = blockIdx.x, b = blockIdx.y, lane = threadIdx.x;
  int q = lane >> 4, l = lane & 15;
  const float* src = h_all + ((size_t)b * LL + c * CS) * HH;

  // ---- stage K rows (bf16 hi/lo) into poolA for the Gram MFMA
#pragma unroll
  for (int i = 0; i < 16; ++i) {
    int row = i * 4 + q;
    float4 v = *(const float4*)&src[row * 64 + l * 4];
    float f[4] = {v.x, v.y, v.z, v.w};
    unsigned hs[4], ls[4];
#pragma unroll
    for (int r = 0; r < 4; ++r) {
      unsigned short hb = f2bf(f[r]);
      float hf = __uint_as_float(((unsigned)hb) << 16);
      hs[r] = hb; ls[r] = f2bf(f[r] - hf);
    }
    *(uint2*)&pA[0][row][l * 4] = make_uint2(hs[0] | (hs[1] << 16), hs[2] | (hs[3] << 16));
    *(uint2*)&pA[1][row][l * 4] = make_uint2(ls[0] | (ls[1] << 16), ls[2] | (ls[3] << 16));
  }
  bl[lane] = beta[(size_t)b * LL + c * CS + lane];
  if (c == NG - 1) { pA[0][63][lane] = 0; pA[1][63][lane] = 0; }  // t=L-1 not a key
  __syncthreads();

  // ---- Gram via split-bf16 MFMA: D[s][t] = sum_h K[s][h] K[t][h]
  f32x4 acc[4][4];
#pragma unroll
  for (int mi = 0; mi < 4; ++mi)
#pragma unroll
    for (int nt = 0; nt < 4; ++nt) acc[mi][nt] = (f32x4){0.f, 0.f, 0.f, 0.f};

#pragma unroll
  for (int ks = 0; ks < 2; ++ks) {
    bf16x8 ah[4], al_[4];
#pragma unroll
    for (int i = 0; i < 4; ++i) {
      U16x8 t;
      t.u = *(const uint4*)&pA[0][i * 16 + l][ks * 32 + q * 8]; ah[i] = t.v;
      t.u = *(const uint4*)&pA[1][i * 16 + l][ks * 32 + q * 8]; al_[i] = t.v;
    }
#pragma unroll
    for (int mi = 0; mi < 4; ++mi)
#pragma unroll
      for (int nt = 0; nt < 4; ++nt) {
        acc[mi][nt] = __builtin_amdgcn_mfma_f32_16x16x32_bf16(ah[mi], ah[nt], acc[mi][nt], 0, 0, 0);
        acc[mi][nt] = __builtin_amdgcn_mfma_f32_16x16x32_bf16(ah[mi], al_[nt], acc[mi][nt], 0, 0, 0);
        acc[mi][nt] = __builtin_amdgcn_mfma_f32_16x16x32_bf16(al_[mi], ah[nt], acc[mi][nt], 0, 0, 0);
      }
  }

  // ---- write Gl[s][t] = beta_s * G into poolB
#pragma unroll
  for (int mi = 0; mi < 4; ++mi) {
    int s0 = mi * 16 + q * 4;
    float4 b4 = *(const float4*)&bl[s0];
#pragma unroll
    for (int nt = 0; nt < 4; ++nt) {
      int t = nt * 16 + l;
      Gl[s0 + 0][t] = acc[mi][nt][0] * b4.x;
      Gl[s0 + 1][t] = acc[mi][nt][1] * b4.y;
      Gl[s0 + 2][t] = acc[mi][nt][2] * b4.z;
      Gl[s0 + 3][t] = acc[mi][nt][3] * b4.w;
    }
  }
  __syncthreads();

  // ---- K column into regs (lane = h); m initial = exact f32 K column
  float m[64];
#pragma unroll
  for (int t = 0; t < 64; ++t) m[t] = src[t * 64 + lane];
  if (c == NG - 1) m[63] = 0.f;

  // ---- build colS = K^T rows (bf16 hi/lo) into poolA from m INITIAL
  //      (poolA's Gram staging is dead: frags were read into registers above)
#pragma unroll
  for (int i = 0; i < 32; ++i) {
    float v0 = m[2 * i], v1 = m[2 * i + 1];
    unsigned short h0 = f2bf(v0), h1 = f2bf(v1);
    float r0 = v0 - __uint_as_float(((unsigned)h0) << 16);
    float r1 = v1 - __uint_as_float(((unsigned)h1) << 16);
    *(unsigned*)&pA[0][lane][2 * i] = (unsigned)h0 | (((unsigned)h1) << 16);
    *(unsigned*)&pA[1][lane][2 * i] = (unsigned)f2bf(r0) | (((unsigned)f2bf(r1)) << 16);
  }

  // ---- m-recurrence (exact f32; uniform float4 LDS reads of Gl rows)
#pragma unroll
  for (int s = 63; s >= 1; --s) {
    float ms = m[s];
    const float* g = &Gl[s][0];
#pragma unroll
    for (int i = 0; i + 3 < s; i += 4) {
      float4 g4 = *(const float4*)(g + i);
      m[i + 0] = fmaf(-g4.x, ms, m[i + 0]);
      m[i + 1] = fmaf(-g4.y, ms, m[i + 1]);
      m[i + 2] = fmaf(-g4.z, ms, m[i + 2]);
      m[i + 3] = fmaf(-g4.w, ms, m[i + 3]);
    }
    for (int t = s & ~3; t < s; ++t) m[t] = fmaf(-g[t], ms, m[t]);
  }

  __syncthreads();  // all Gl reads done before (beta M)^T overwrites poolB

  // ---- write (beta M)^T rows (bf16 hi/lo) into poolB
#pragma unroll
  for (int i = 0; i < 32; ++i) {
    float v0 = bl[2 * i] * m[2 * i];
    float v1 = bl[2 * i + 1] * m[2 * i + 1];
    unsigned short h0 = f2bf(v0), h1 = f2bf(v1);
    float r0 = v0 - __uint_as_float(((unsigned)h0) << 16);
    float r1 = v1 - __uint_as_float(((unsigned)h1) << 16);
    *(unsigned*)&pB[0][lane][2 * i] = (unsigned)h0 | (((unsigned)h1) << 16);
    *(unsigned*)&pB[1][lane][2 * i] = (unsigned)f2bf(r0) | (((unsigned)f2bf(r1)) << 16);
  }
  __syncthreads();

  // ---- N MFMA: D2[h][h'] = sum_t KT[h][t] * (beta_t m_t[h']);  N = I - D2
  f32x4 acc2[4][4];
#pragma unroll
  for (int mi = 0; mi < 4; ++mi)
#pragma unroll
    for (int nt = 0; nt < 4; ++nt) acc2[mi][nt] = (f32x4){0.f, 0.f, 0.f, 0.f};

#pragma unroll
  for (int ks = 0; ks < 2; ++ks) {
    bf16x8 ah[4], al_[4], bh[4], blo[4];
#pragma unroll
    for (int i = 0; i < 4; ++i) {
      U16x8 t;
      t.u = *(const uint4*)&pA[0][i * 16 + l][ks * 32 + q * 8]; ah[i] = t.v;
      t.u = *(const uint4*)&pA[1][i * 16 + l][ks * 32 + q * 8]; al_[i] = t.v;
      t.u = *(const uint4*)&pB[0][i * 16 + l][ks * 32 + q * 8]; bh[i] = t.v;
      t.u = *(const uint4*)&pB[1][i * 16 + l][ks * 32 + q * 8]; blo[i] = t.v;
    }
#pragma unroll
    for (int mi = 0; mi < 4; ++mi)
#pragma unroll
      for (int nt = 0; nt < 4; ++nt) {
        acc2[mi][nt] = __builtin_amdgcn_mfma_f32_16x16x32_bf16(ah[mi], bh[nt], acc2[mi][nt], 0, 0, 0);
        acc2[mi][nt] = __builtin_amdgcn_mfma_f32_16x16x32_bf16(ah[mi], blo[nt], acc2[mi][nt], 0, 0, 0);
        acc2[mi][nt] = __builtin_amdgcn_mfma_f32_16x16x32_bf16(al_[mi], bh[nt], acc2[mi][nt], 0, 0, 0);
      }
  }

  // store TRANSPOSED: Ng[j*64 + h] = N[h][j]  (float4 over h)
  float* np = Ng + (((size_t)b * NG + c) << 12);
#pragma unroll
  for (int mi = 0; mi < 4; ++mi)
#pragma unroll
    for (int nt = 0; nt < 4; ++nt) {
      int h0 = mi * 16 + q * 4, hp = nt * 16 + l;
      float4 v;
      v.x = ((h0 + 0 == hp) ? 1.f : 0.f) - acc2[mi][nt][0];
      v.y = ((h0 + 1 == hp) ? 1.f : 0.f) - acc2[mi][nt][1];
      v.z = ((h0 + 2 == hp) ? 1.f : 0.f) - acc2[mi][nt][2];
      v.w = ((h0 + 3 == hp) ? 1.f : 0.f) - acc2[mi][nt][3];
      *(float4*)&np[hp * 64 + h0] = v;
    }
}

// ---------------- Kernel 3: boundary — LDS double-buffered matvec (unchanged) -----
__global__ __launch_bounds__(64, 1) void boundary_kernel(
    const float* __restrict__ h_all, const float* __restrict__ Ng,
    const int* __restrict__ read_pos_p, float* __restrict__ Qg) {
  __shared__ __align__(16) float nt0[64 * 64];
  __shared__ __align__(16) float nt1[64 * 64];
  __shared__ __align__(16) float ql[64];

  int b = blockIdx.x, lane = threadIdx.x;
  int rpv = read_pos_p[0];
  int pos = rpv < 0 ? rpv + LL : rpv;
  float Q = h_all[((size_t)b * LL + pos) * HH + lane];

  const float* Nb = Ng + ((size_t)b * NG << 12);

  auto load_chunk = [&](float* buf, int c) {
    const float* g = Nb + ((size_t)c << 12);
#pragma unroll
    for (int i = 0; i < 16; ++i)
      __builtin_amdgcn_global_load_lds(
          (const __attribute__((address_space(1))) unsigned*)(g + i * 256 + lane * 4),
          (__attribute__((address_space(3))) unsigned*)(buf + i * 256), 16, 0, 0);
  };

  auto step = [&](const float* buf, int c, bool last) {
    if (last) __builtin_amdgcn_s_waitcnt(0x0F70);  // vmcnt(0)
    else      __builtin_amdgcn_s_waitcnt(0x4F70);  // vmcnt(16)
    Qg[((size_t)b * NG + c) * HH + lane] = Q;
    ql[lane] = Q;
    float a0 = 0.f, a1 = 0.f, a2 = 0.f, a3 = 0.f;
#pragma unroll
    for (int j = 0; j < 64; j += 4) {
      float4 q4 = *(const float4*)&ql[j];  // uniform LDS broadcast
      a0 = fmaf(buf[(j + 0) * 64 + lane], q4.x, a0);
      a1 = fmaf(buf[(j + 1) * 64 + lane], q4.y, a1);
      a2 = fmaf(buf[(j + 2) * 64 + lane], q4.z, a2);
      a3 = fmaf(buf[(j + 3) * 64 + lane], q4.w, a3);
    }
    Q = (a0 + a1) + (a2 + a3);
  };

  load_chunk(nt1, NG - 1);
  load_chunk(nt0, NG - 2);

#pragma unroll 1
  for (int c = NG - 1; c >= 1; c -= 2) {
    step(nt1, c, false);
    __builtin_amdgcn_s_waitcnt(0xC07F);  // lgkmcnt(0)
    if (c >= 3) load_chunk(nt1, c - 2);
    step(nt0, c - 1, c == 1);
    __builtin_amdgcn_s_waitcnt(0xC07F);
    if (c >= 3) load_chunk(nt0, c - 3);
  }
}

// ---------------- Kernel 4 (phase 3): parallel within-chunk r accumulation -------
__global__ __launch_bounds__(64, 1) void chunk_scan_kernel(
    const float* __restrict__ h_all, const float* __restrict__ beta,
    const float* __restrict__ Qg, float* __restrict__ rc) {
  int c = blockIdx.x, b = blockIdx.y, j = threadIdx.x;
  const float* hb = h_all + (size_t)b * LL * HH;
  const float* betab = beta + (size_t)b * LL;

  float P = Qg[((size_t)b * NG + c) * HH + j];
  float r = 0.f;

  float kk[CS];
#pragma unroll
  for (int i = 0; i < CS; ++i) kk[i] = hb[((size_t)(c * CS + i)) * HH + j];
  float bv = betab[c * CS + j];

  bool last = (c == NG - 1);
#pragma unroll
  for (int i = CS - 1; i >= 0; --i) {
    float k = kk[i];
    float bt = readlane_f(bv, i);
    float m = k * P;
    float s = wave_sum_lane63(m);
    float d = readlane_f(s, 63);
    if (i == CS - 1 && last) d = 0.f;
    r = fmaf(d, k, r);
    P = fmaf(-(bt * d), k, P);
  }
  rc[((size_t)b * NG + c) * HH + j] = r;
}

// ---------------- Kernel 5: combine r over chunks, y = r @ rp_w + rp_b ----------
__global__ __launch_bounds__(64, 1) void combine_kernel(
    const float* __restrict__ rc, const float* __restrict__ rp_w,
    const float* __restrict__ rp_b, float* __restrict__ yv) {
  int b = blockIdx.x, j = threadIdx.x;
  float r = 0.f;
#pragma unroll 8
  for (int cc = 0; cc < NG; ++cc) r += rc[((size_t)b * NG + cc) * HH + j];
  __shared__ float rs[HH];
  rs[j] = r;
  __syncthreads();
  float yj = rp_b[j];
#pragma unroll
  for (int h = 0; h < HH; ++h) yj = fmaf(rs[h], rp_w[h * HH + j], yj);
  yv[b * HH + j] = yj;
}

// ---------------- Kernel 6: output GEMM ----------------
__global__ __launch_bounds__(256, 2) void out_kernel(
    const float* __restrict__ yv, const float* __restrict__ out_w,
    const float* __restrict__ out_b, float* __restrict__ out) {
  __shared__ float ys[BB * HH];
  for (int i = threadIdx.x; i < BB * HH; i += 256) ys[i] = yv[i];
  __syncthreads();

  int v = blockIdx.x * 256 + threadIdx.x;
  if (v >= VV) return;

  float acc[BB];
  float ob = out_b[v];
#pragma unroll
  for (int b = 0; b < BB; ++b) acc[b] = ob;

  for (int h = 0; h < HH; ++h) {
    float w = out_w[(size_t)h * VV + v];
#pragma unroll
    for (int b = 0; b < BB; ++b) acc[b] = fmaf(ys[b * HH + h], w, acc[b]);
  }
#pragma unroll
  for (int b = 0; b < BB; ++b) out[(size_t)b * VV + v] = acc[b];
}

// ---------------- launch ----------------
extern "C" void kernel_launch(void* const* d_in, const int* in_sizes, int n_in,
                              void* d_out, int out_size, void* d_ws, size_t ws_size,
                              hipStream_t stream) {
  (void)in_sizes; (void)n_in; (void)out_size; (void)ws_size;
  const int*   seq   = (const int*)d_in[0];
  const int*   rp    = (const int*)d_in[1];
  const float* embed = (const float*)d_in[2];
  const float* w1    = (const float*)d_in[3];
  const float* b1    = (const float*)d_in[4];
  const float* w2    = (const float*)d_in[5];
  const float* b2    = (const float*)d_in[6];
  const float* ln_g  = (const float*)d_in[7];
  const float* ln_b  = (const float*)d_in[8];
  const float* rp_w  = (const float*)d_in[9];
  const float* rp_b  = (const float*)d_in[10];
  const float* out_w = (const float*)d_in[11];
  const float* out_b = (const float*)d_in[12];
  float* out = (float*)d_out;

  // workspace layout (~68.6 MB)
  float* h_all = (float*)d_ws;                               // B*L*H
  float* beta  = h_all + (size_t)BB * LL * HH;               // B*L
  float* Ng    = beta + (size_t)BB * LL;                     // B*NG*H*H (32 MB, N^T)
  float* Qg    = Ng + (size_t)BB * NG * HH * HH;             // B*NG*H
  float* rcv   = Qg + (size_t)BB * NG * HH;                  // B*NG*H
  float* yv    = rcv + (size_t)BB * NG * HH;                 // B*H
  unsigned short* w1b = (unsigned short*)(yv + (size_t)BB * HH);  // 128*64 bf16
  unsigned short* w2b = w1b + 8192;                               // 64*128 bf16

  prep_kernel<<<64, 256, 0, stream>>>(w1, w2, w1b, w2b);
  encoder_kernel<<<BB * LL / 64, 64, 0, stream>>>(seq, embed, w1b, b1, w2b, b2,
                                                  ln_g, ln_b, h_all, beta);
  gram_n_kernel<<<dim3(NG, BB), 64, 0, stream>>>(h_all, beta, Ng);
  boundary_kernel<<<BB, 64, 0, stream>>>(h_all, Ng, rp, Qg);
  chunk_scan_kernel<<<dim3(NG, BB), 64, 0, stream>>>(h_all, beta, Qg, rcv);
  combine_kernel<<<BB, 64, 0, stream>>>(rcv, rp_w, rp_b, yv);
  out_kernel<<<(VV + 255) / 256, 256, 0, stream>>>(yv, out_w, out_b, out);
}